// Round 6
// baseline (180.533 us; speedup 1.0000x reference)
//
#include <hip/hip_runtime.h>
#include <hip/hip_bf16.h>

// PointNet2 FP: 3-NN + interp + concat + MLP(384->256->128), bf16 MFMA
// R6: MEASUREMENT ROUND. Split the fused kernel at the phase boundary into
// knn_kernel (phase 1, writes idx/weights to workspace) and mlp_kernel
// (phase 2, reads them). Phase internals are byte-identical to R5 — the
// split turns rocprof per-dispatch timing into a direct phase ablation
// (5 flat theory rounds => measure, don't guess).
#define BB 2
#define NN 16384
#define MM 4096
#define C1 128
#define C2 256
#define CIN 384
#define H1 256
#define H2 128
#define XROW 392       // 384 + 8 pad
#define HROW 264       // 256 + 8 pad

typedef __attribute__((ext_vector_type(8))) short bf16x8;
typedef __attribute__((ext_vector_type(4))) float f32x4;
typedef __attribute__((ext_vector_type(2))) float f32x2;

__device__ __forceinline__ short f32_to_bf16(float x) {
    unsigned u = __float_as_uint(x);
    u += 0x7fffu + ((u >> 16) & 1u);   // RNE
    return (short)(u >> 16);
}
__device__ __forceinline__ float bf16_to_f32(unsigned short u) {
    union { unsigned u; float f; } c; c.u = ((unsigned)u) << 16; return c.f;
}
__device__ __forceinline__ unsigned pack_bf16x2(float a, float b) {
    __hip_bfloat162 h = __float22bfloat162_rn(make_float2(a, b));
    union { __hip_bfloat162 h; unsigned u; } cv;
    cv.h = h;
    return cv.u;
}
// score PAIR from SoA components; n recomputed. MUST be bit-identical
// between pass A and the rescan: same elementwise-fma chain.
__device__ __forceinline__ f32x2 score2n(f32x2 ax2, f32x2 ay2, f32x2 az2,
                                         f32x2 x, f32x2 y, f32x2 z) {
    f32x2 n = __builtin_elementwise_fma(x, x,
              __builtin_elementwise_fma(y, y, z * z));
    f32x2 t = __builtin_elementwise_fma(az2, z, n);
    t = __builtin_elementwise_fma(ay2, y, t);
    t = __builtin_elementwise_fma(ax2, x, t);
    return t;
}

// ---------------- Kernel 1: prep — transpose + weight cast + kxyz --------
__global__ __launch_bounds__(256) void prep_kernel(
    const float* __restrict__ KF, unsigned short* __restrict__ KT16,
    const float* __restrict__ W1, const float* __restrict__ W2,
    short* __restrict__ W1b, short* __restrict__ W2b,
    const float* __restrict__ known, float* __restrict__ kxyz)
{
    const int bx  = blockIdx.x;
    const int tid = threadIdx.x;
    if (bx < 2048) {
        __shared__ float tl[32][33];
        const int b  = bx >> 10;
        const int c0 = ((bx >> 7) & 7) * 32;
        const int m0 = (bx & 127) * 32;
        const int tx = tid & 31;
        const int ty = tid >> 5;            // 0..7
        #pragma unroll
        for (int r = 0; r < 4; ++r) {
            int c = ty + r * 8;
            tl[c][tx] = KF[((size_t)b * C2 + c0 + c) * MM + m0 + tx];
        }
        __syncthreads();
        #pragma unroll
        for (int r = 0; r < 4; ++r) {
            int m = ty + r * 8;
            KT16[((size_t)b * MM + m0 + m) * C2 + c0 + tx] =
                (unsigned short)f32_to_bf16(tl[tx][m]);
        }
    } else if (bx < 2432) {
        int i = (bx - 2048) * 256 + tid;
        if (i < H1 * CIN) W1b[i] = f32_to_bf16(W1[i]);
        if (i < H2 * H1)  W2b[i] = f32_to_bf16(W2[i]);
    } else {
        // kxyz: SoA by 256-candidate slice: [b][slice(16)][comp(3)][256]
        int i = (bx - 2432) * 256 + tid;
        if (i < BB * MM) {
            float x = known[3 * i + 0], y = known[3 * i + 1], z = known[3 * i + 2];
            int b = i >> 12;              // /MM
            int c = i & (MM - 1);
            int slice = c >> 8;
            int pos   = c & 255;
            float* base = kxyz + (size_t)b * 12288 + slice * 768;
            base[pos] = x; base[256 + pos] = y; base[512 + pos] = z;
        }
    }
}

// -------------------- Kernel 2: 3-NN (phase 1 of R5) ---------------------
// grid 512, block 1024 (16 waves). Block owns 64 queries. Single SoA scan
// (3 b128 / 4 cands) + 64-bit super-group marks + sparse rescan. Writes
// idx/weights per point to workspace.
__global__ __launch_bounds__(1024, 8) void knn_kernel(
    const float* __restrict__ unknown,        // (B,N,3)
    const float* __restrict__ kxyz,           // SoA candidates
    int*   __restrict__ idxW,                 // (B,N,3)
    float* __restrict__ wgtW)                 // (B,N,3)
{
    __shared__ __align__(16) float candS[12288];  // 48KB SoA
    __shared__ __align__(16) float red[3072];     // pdv | msc/mid alias
    __shared__ float vf[64];
    __shared__ int   cnt[64];

    const int bx    = blockIdx.x;             // 0..511
    const int tid   = threadIdx.x;
    const int lane  = tid & 63;
    const int w     = __builtin_amdgcn_readfirstlane(tid >> 6);  // 0..15
    const int b     = bx >> 8;
    const int qbase = (bx & 255) * 64;
    const int n     = qbase + lane;

    if (tid < 64) cnt[tid] = 0;

    // ---- stage SoA candidates (48KB) into LDS, coalesced f32x4 ----
    {
        const float* kb = kxyz + (size_t)b * 12288;
        #pragma unroll
        for (int c = 0; c < 3; ++c) {
            const int i = c * 4096 + tid * 4;
            *(f32x4*)&candS[i] = *(const f32x4*)(kb + i);
        }
    }

    const float ux = unknown[((size_t)b * NN + n) * 3 + 0];
    const float uy = unknown[((size_t)b * NN + n) * 3 + 1];
    const float uz = unknown[((size_t)b * NN + n) * 3 + 2];
    const f32x2 ax2 = {-2.f * ux, -2.f * ux};
    const f32x2 ay2 = {-2.f * uy, -2.f * uy};
    const f32x2 az2 = {-2.f * uz, -2.f * uz};

    const float* kw = candS + w * 768;    // slice: x[256] y[256] z[256]
    __syncthreads();                      // staging visible to all waves

    // Pass A: 64 super-groups x 4 candidates; mark supers that touch a
    // running top-3 (marks BEFORE the update; running v2 only decreases).
    float va0 = 3e38f, va1 = 3e38f, va2 = 3e38f;
    float vb0 = 3e38f, vb1 = 3e38f, vb2 = 3e38f;
    unsigned long long mm = 0ull;
    #pragma unroll 2
    for (int t = 0; t < 64; ++t) {
        const f32x4 X = *(const f32x4*)(kw + 4 * t);
        const f32x4 Y = *(const f32x4*)(kw + 256 + 4 * t);
        const f32x4 Z = *(const f32x4*)(kw + 512 + 4 * t);
        const f32x2 xl = {X.x, X.y}, xh = {X.z, X.w};
        const f32x2 yl = {Y.x, Y.y}, yh = {Y.z, Y.w};
        const f32x2 zl = {Z.x, Z.y}, zh = {Z.z, Z.w};
        const f32x2 sl = score2n(ax2, ay2, az2, xl, yl, zl);  // c0,c1
        const f32x2 sh = score2n(ax2, ay2, az2, xh, yh, zh);  // c2,c3
        bool m0 = sl.x <= va2;
        va2 = __builtin_amdgcn_fmed3f(va1, sl.x, va2);
        va1 = __builtin_amdgcn_fmed3f(va0, sl.x, va1);
        va0 = fminf(sl.x, va0);
        bool m1 = sl.y <= vb2;
        vb2 = __builtin_amdgcn_fmed3f(vb1, sl.y, vb2);
        vb1 = __builtin_amdgcn_fmed3f(vb0, sl.y, vb1);
        vb0 = fminf(sl.y, vb0);
        bool m2 = sh.x <= va2;
        va2 = __builtin_amdgcn_fmed3f(va1, sh.x, va2);
        va1 = __builtin_amdgcn_fmed3f(va0, sh.x, va1);
        va0 = fminf(sh.x, va0);
        bool m3 = sh.y <= vb2;
        vb2 = __builtin_amdgcn_fmed3f(vb1, sh.y, vb2);
        vb1 = __builtin_amdgcn_fmed3f(vb0, sh.y, vb1);
        vb0 = fminf(sh.y, vb0);
        mm |= ((unsigned long long)(m0 | m1 | m2 | m3)) << t;
    }
    {   // fold chain b into chain a
        float bv[3] = {vb0, vb1, vb2};
        #pragma unroll
        for (int k = 0; k < 3; ++k) {
            float d = bv[k];
            va2 = __builtin_amdgcn_fmed3f(va1, d, va2);
            va1 = __builtin_amdgcn_fmed3f(va0, d, va1);
            va0 = fminf(d, va0);
        }
    }
    red[(w * 64 + lane) * 3 + 0] = va0;
    red[(w * 64 + lane) * 3 + 1] = va1;
    red[(w * 64 + lane) * 3 + 2] = va2;
    __syncthreads();

    if (tid < 64) {
        float r0 = 3e38f, r1 = 3e38f, r2 = 3e38f;
        #pragma unroll
        for (int ww = 0; ww < 16; ++ww) {
            #pragma unroll
            for (int k = 0; k < 3; ++k) {
                float d = red[(ww * 64 + tid) * 3 + k];
                r2 = __builtin_amdgcn_fmed3f(r1, d, r2);
                r1 = __builtin_amdgcn_fmed3f(r0, d, r1);
                r0 = fminf(d, r0);
            }
        }
        vf[tid] = r2;
    }
    __syncthreads();

    // Sparse rescan of marked supers (bit-identical score chain).
    float* mscp = red;                    // [64][8] f32 (aliases dead pdv)
    int*   midp = (int*)red + 512;        // [64][8] int
    const float v2f = vf[lane];
    unsigned long long m = mm;
    while (m) {
        const int t = (int)__builtin_ctzll(m);
        m &= m - 1;
        const f32x4 X = *(const f32x4*)(kw + 4 * t);
        const f32x4 Y = *(const f32x4*)(kw + 256 + 4 * t);
        const f32x4 Z = *(const f32x4*)(kw + 512 + 4 * t);
        const f32x2 xl = {X.x, X.y}, xh = {X.z, X.w};
        const f32x2 yl = {Y.x, Y.y}, yh = {Y.z, Y.w};
        const f32x2 zl = {Z.x, Z.y}, zh = {Z.z, Z.w};
        const f32x2 sl = score2n(ax2, ay2, az2, xl, yl, zl);
        const f32x2 sh = score2n(ax2, ay2, az2, xh, yh, zh);
        const float sv[4] = {sl.x, sl.y, sh.x, sh.y};
        #pragma unroll
        for (int j = 0; j < 4; ++j) {
            if (sv[j] <= v2f) {
                int slot = atomicAdd(&cnt[lane], 1);
                if (slot < 8) {
                    mscp[lane * 8 + slot] = sv[j];
                    midp[lane * 8 + slot] = w * 256 + 4 * t + j;
                }
            }
        }
    }
    __syncthreads();

    if (tid < 64) {
        const int c = cnt[tid] < 8 ? cnt[tid] : 8;
        float r0 = 3e38f, r1 = 3e38f, r2 = 3e38f;
        int   q0 = 0x7FFFFFFF, q1 = 0x7FFFFFFF, q2 = 0x7FFFFFFF;
        #pragma unroll
        for (int k = 0; k < 8; ++k) {
            float d = (k < c) ? mscp[tid * 8 + k] : 3e38f;
            int   j = (k < c) ? midp[tid * 8 + k] : 0x7FFFFFFF;
            const bool lt0 = (d < r0) || (d == r0 && j < q0);
            const bool lt1 = (d < r1) || (d == r1 && j < q1);
            const bool lt2 = (d < r2) || (d == r2 && j < q2);
            float nr2 = lt1 ? r1 : (lt2 ? d : r2);
            int   nq2 = lt1 ? q1 : (lt2 ? j : q2);
            float nr1 = lt0 ? r0 : (lt1 ? d : r1);
            int   nq1 = lt0 ? q0 : (lt1 ? j : q1);
            float nr0 = lt0 ? d : r0;
            int   nq0 = lt0 ? j : q0;
            r0 = nr0; r1 = nr1; r2 = nr2; q0 = nq0; q1 = nq1; q2 = nq2;
        }
        const float* up = unknown + ((size_t)b * NN + qbase + tid) * 3;
        const float uxx = up[0], uyy = up[1], uzz = up[2];
        const float unq = fmaf(uxx, uxx, fmaf(uyy, uyy, uzz * uzz));
        float d0 = sqrtf(fmaxf(r0 + unq, 0.f));
        float d1 = sqrtf(fmaxf(r1 + unq, 0.f));
        float d2 = sqrtf(fmaxf(r2 + unq, 0.f));
        float i0 = 1.f / (d0 + 1e-8f);
        float i1 = 1.f / (d1 + 1e-8f);
        float i2 = 1.f / (d2 + 1e-8f);
        float s  = i0 + i1 + i2;
        const size_t o = ((size_t)b * NN + qbase + tid) * 3;
        idxW[o + 0] = q0; idxW[o + 1] = q1; idxW[o + 2] = q2;
        wgtW[o + 0] = i0 / s; wgtW[o + 1] = i1 / s; wgtW[o + 2] = i2 / s;
    }
}

// ------------- Kernel 3: gather-interp + 2-layer MFMA MLP ---------------
// grid 512, block 1024 (16 waves). Block owns 64 points, 2 tiles of 32.
// Identical to R5 phase 2; idx/weights come from workspace (wave-uniform
// scalar loads, 6 per wave per tile).
__global__ __launch_bounds__(1024, 8) void mlp_kernel(
    const int*   __restrict__ idxW,           // (B,N,3)
    const float* __restrict__ wgtW,           // (B,N,3)
    const float* __restrict__ unknow_feats,   // (B,C1,N)
    const unsigned short* __restrict__ KT16,  // (B,M,C2) bf16
    const short* __restrict__ W1b, const float* __restrict__ b1,
    const short* __restrict__ W2b, const float* __restrict__ b2,
    float* __restrict__ out)                  // (B,H2,N)
{
    __shared__ short XH_s[32 * XROW];         // 25088 B
    __shared__ short Hs_s[32 * HROW];         // 16896 B

    const int bx    = blockIdx.x;             // 0..511
    const int tid   = threadIdx.x;
    const int lane  = tid & 63;
    const int w     = __builtin_amdgcn_readfirstlane(tid >> 6);  // 0..15
    const int b     = bx >> 8;
    const int qbase = (bx & 255) * 64;

    const unsigned short* KTb = KT16 + (size_t)b * MM * C2;
    const int lr = lane & 15;
    const int lq = lane >> 4;
    const int c4 = lane << 2;                 // 0..252

    for (int tile = 0; tile < 2; ++tile) {
        const int pbase = tile * 32;

        // ---- X build: wave w -> local points 2w, 2w+1 (issue all 6 gathers)
        {
            int   I[2][3];
            float W[2][3];
            #pragma unroll
            for (int j = 0; j < 2; ++j) {
                const size_t o = ((size_t)b * NN + qbase + pbase + 2 * w + j) * 3;
                I[j][0] = idxW[o + 0]; I[j][1] = idxW[o + 1]; I[j][2] = idxW[o + 2];
                W[j][0] = wgtW[o + 0]; W[j][1] = wgtW[o + 1]; W[j][2] = wgtW[o + 2];
            }
            ushort4 g[2][3];
            #pragma unroll
            for (int j = 0; j < 2; ++j) {
                g[j][0] = *(const ushort4*)(KTb + (size_t)I[j][0] * C2 + c4);
                g[j][1] = *(const ushort4*)(KTb + (size_t)I[j][1] * C2 + c4);
                g[j][2] = *(const ushort4*)(KTb + (size_t)I[j][2] * C2 + c4);
            }
            #pragma unroll
            for (int j = 0; j < 2; ++j) {
                const int pl = 2 * w + j;
                const float w0 = W[j][0], w1 = W[j][1], w2 = W[j][2];
                float vx = fmaf(w0, bf16_to_f32(g[j][0].x), fmaf(w1, bf16_to_f32(g[j][1].x), w2 * bf16_to_f32(g[j][2].x)));
                float vy = fmaf(w0, bf16_to_f32(g[j][0].y), fmaf(w1, bf16_to_f32(g[j][1].y), w2 * bf16_to_f32(g[j][2].y)));
                float vz = fmaf(w0, bf16_to_f32(g[j][0].z), fmaf(w1, bf16_to_f32(g[j][1].z), w2 * bf16_to_f32(g[j][2].z)));
                float vw = fmaf(w0, bf16_to_f32(g[j][0].w), fmaf(w1, bf16_to_f32(g[j][1].w), w2 * bf16_to_f32(g[j][2].w)));
                uint2 pk;
                pk.x = pack_bf16x2(vx, vy);
                pk.y = pack_bf16x2(vz, vw);
                *(uint2*)&XH_s[pl * XROW + c4] = pk;
            }
            const float* UFb = unknow_feats + (size_t)b * C1 * NN + qbase + pbase;
            const int cc = tid >> 3;              // 0..127
            const int nq = (tid & 7) << 2;        // 0,4,..,28
            const float4 f = *(const float4*)(UFb + (size_t)cc * NN + nq);
            XH_s[(nq + 0) * XROW + C2 + cc] = f32_to_bf16(f.x);
            XH_s[(nq + 1) * XROW + C2 + cc] = f32_to_bf16(f.y);
            XH_s[(nq + 2) * XROW + C2 + cc] = f32_to_bf16(f.z);
            XH_s[(nq + 3) * XROW + C2 + cc] = f32_to_bf16(f.w);
        }
        __syncthreads();

        // ---- GEMM1: wave w -> H1 rows [16w, 16w+16), 32 points ----
        f32x4 acc1[2];
        acc1[0] = (f32x4){0.f, 0.f, 0.f, 0.f};
        acc1[1] = (f32x4){0.f, 0.f, 0.f, 0.f};
        #pragma unroll 4
        for (int k0 = 0; k0 < CIN; k0 += 32) {
            bf16x8 a  = *(const bf16x8*)(W1b + (size_t)(w * 16 + lr) * CIN + k0 + lq * 8);
            bf16x8 x0 = *(bf16x8*)&XH_s[lr * XROW + k0 + lq * 8];
            bf16x8 x1 = *(bf16x8*)&XH_s[(16 + lr) * XROW + k0 + lq * 8];
            acc1[0] = __builtin_amdgcn_mfma_f32_16x16x32_bf16(a, x0, acc1[0], 0, 0, 0);
            acc1[1] = __builtin_amdgcn_mfma_f32_16x16x32_bf16(a, x1, acc1[1], 0, 0, 0);
        }
        {
            const int ob = w * 16 + lq * 4;
            float bb0 = b1[ob + 0], bb1 = b1[ob + 1], bb2 = b1[ob + 2], bb3 = b1[ob + 3];
            #pragma unroll
            for (int p = 0; p < 2; ++p) {
                uint2 pk;
                pk.x = pack_bf16x2(fmaxf(acc1[p].x + bb0, 0.f),
                                   fmaxf(acc1[p].y + bb1, 0.f));
                pk.y = pack_bf16x2(fmaxf(acc1[p].z + bb2, 0.f),
                                   fmaxf(acc1[p].w + bb3, 0.f));
                *(uint2*)&Hs_s[(p * 16 + lr) * HROW + ob] = pk;
            }
        }
        __syncthreads();

        // ---- GEMM2: wave w -> H2 rows [16(w&7),+16), points [16(w>>3),+16)
        {
            const int r0 = (w & 7) * 16;
            const int pg = (w >> 3) * 16;
            f32x4 acc2 = (f32x4){0.f, 0.f, 0.f, 0.f};
            #pragma unroll 4
            for (int k0 = 0; k0 < H1; k0 += 32) {
                bf16x8 a2 = *(const bf16x8*)(W2b + (size_t)(r0 + lr) * H1 + k0 + lq * 8);
                bf16x8 h  = *(bf16x8*)&Hs_s[(pg + lr) * HROW + k0 + lq * 8];
                acc2 = __builtin_amdgcn_mfma_f32_16x16x32_bf16(a2, h, acc2, 0, 0, 0);
            }
            const int nn = qbase + pbase + pg + lr;
            #pragma unroll
            for (int r = 0; r < 4; ++r) {
                const int o = r0 + lq * 4 + r;
                out[((size_t)b * H2 + o) * NN + nn] =
                    fmaxf(((const float*)&acc2)[r] + b2[o], 0.f);
            }
        }
        __syncthreads();   // Hs/XH free for next tile
    }
}

extern "C" void kernel_launch(void* const* d_in, const int* in_sizes, int n_in,
                              void* d_out, int out_size, void* d_ws, size_t ws_size,
                              hipStream_t stream) {
    const float* unknown      = (const float*)d_in[0];
    const float* known        = (const float*)d_in[1];
    const float* unknow_feats = (const float*)d_in[2];
    const float* known_feats  = (const float*)d_in[3];
    const float* W1           = (const float*)d_in[4];
    const float* b1           = (const float*)d_in[5];
    const float* W2           = (const float*)d_in[6];
    const float* b2           = (const float*)d_in[7];
    float* out = (float*)d_out;

    char* ws = (char*)d_ws;
    short*          W1b  = (short*)(ws);                    // 196608 B
    short*          W2b  = (short*)(ws + 196608);           // 65536 B
    float*          kxyz = (float*)(ws + 262144);           // 98304 B
    unsigned short* KT16 = (unsigned short*)(ws + 393216);  // 4194304 B
    int*            idxW = (int*)(ws + 4587520);            // 393216 B
    float*          wgtW = (float*)(ws + 4980736);          // 393216 B

    prep_kernel<<<2464, 256, 0, stream>>>(
        known_feats, KT16, W1, W2, W1b, W2b, known, kxyz);

    knn_kernel<<<512, 1024, 0, stream>>>(unknown, kxyz, idxW, wgtW);

    mlp_kernel<<<512, 1024, 0, stream>>>(
        idxW, wgtW, unknow_feats, KT16, W1b, b1, W2b, b2, out);
}

// Round 8
// 157.656 us; speedup vs baseline: 1.1451x; 1.1451x over previous
//
#include <hip/hip_runtime.h>
#include <hip/hip_bf16.h>

// PointNet2 FP: fused 3-NN + interp + concat + MLP(384->256->128), bf16 MFMA
// R8: R5's verified 2-launch structure + VALU diet in the scan (R6 measured
// knn VALU-issue-bound: 67% busy, 0.3% HBM, 0 MFMA). Changes vs R5:
//  (1) precomputed ||k||^2 back in SoA (4-comp, 128KB): 3 pk-fma / 2 cand.
//  (2) per-SUPER conservative mark (min4(s) <= fmax(va2,vb2) pre-update,
//      ~7 ops vs ~15) into two u32 masks; rescan re-filters exactly vs v2f
//      with the bit-identical score chain.
// R7's cooperative mega-kernel failed cross-XCD prep->consume coherence;
// kernel-boundary handoff restored.
#define BB 2
#define NN 16384
#define MM 4096
#define C1 128
#define C2 256
#define CIN 384
#define H1 256
#define H2 128
#define XROW 392       // 384 + 8 pad
#define HROW 264       // 256 + 8 pad

typedef __attribute__((ext_vector_type(8))) short bf16x8;
typedef __attribute__((ext_vector_type(4))) float f32x4;
typedef __attribute__((ext_vector_type(2))) float f32x2;

__device__ __forceinline__ short f32_to_bf16(float x) {
    unsigned u = __float_as_uint(x);
    u += 0x7fffu + ((u >> 16) & 1u);   // RNE
    return (short)(u >> 16);
}
__device__ __forceinline__ float bf16_to_f32(unsigned short u) {
    union { unsigned u; float f; } c; c.u = ((unsigned)u) << 16; return c.f;
}
__device__ __forceinline__ unsigned pack_bf16x2(float a, float b) {
    __hip_bfloat162 h = __float22bfloat162_rn(make_float2(a, b));
    union { __hip_bfloat162 h; unsigned u; } cv;
    cv.h = h;
    return cv.u;
}
// score PAIR with precomputed kn. MUST be bit-identical between pass A and
// the rescan (same explicit fma DAG).
__device__ __forceinline__ f32x2 score2k(f32x2 ax2, f32x2 ay2, f32x2 az2,
                                         f32x2 kx, f32x2 ky, f32x2 kz, f32x2 kn) {
    f32x2 t = __builtin_elementwise_fma(ay2, ky, kn);
    t = __builtin_elementwise_fma(ax2, kx, t);
    t = __builtin_elementwise_fma(az2, kz, t);
    return t;
}

// ---------------- Kernel 1: prep — transpose + weight cast + kxyz --------
__global__ __launch_bounds__(256) void prep_kernel(
    const float* __restrict__ KF, unsigned short* __restrict__ KT16,
    const float* __restrict__ W1, const float* __restrict__ W2,
    short* __restrict__ W1b, short* __restrict__ W2b,
    const float* __restrict__ known, float* __restrict__ kxyz)
{
    const int bx  = blockIdx.x;
    const int tid = threadIdx.x;
    if (bx < 2048) {
        __shared__ float tl[32][33];
        const int b  = bx >> 10;
        const int c0 = ((bx >> 7) & 7) * 32;
        const int m0 = (bx & 127) * 32;
        const int tx = tid & 31;
        const int ty = tid >> 5;            // 0..7
        #pragma unroll
        for (int r = 0; r < 4; ++r) {
            int c = ty + r * 8;
            tl[c][tx] = KF[((size_t)b * C2 + c0 + c) * MM + m0 + tx];
        }
        __syncthreads();
        #pragma unroll
        for (int r = 0; r < 4; ++r) {
            int m = ty + r * 8;
            KT16[((size_t)b * MM + m0 + m) * C2 + c0 + tx] =
                (unsigned short)f32_to_bf16(tl[tx][m]);
        }
    } else if (bx < 2432) {
        int i = (bx - 2048) * 256 + tid;
        if (i < H1 * CIN) W1b[i] = f32_to_bf16(W1[i]);
        if (i < H2 * H1)  W2b[i] = f32_to_bf16(W2[i]);
    } else {
        // kxyz: SoA by 256-candidate slice: [b][slice(16)][comp(4)][256]
        int i = (bx - 2432) * 256 + tid;
        if (i < BB * MM) {
            float x = known[3 * i + 0], y = known[3 * i + 1], z = known[3 * i + 2];
            float n = fmaf(x, x, fmaf(y, y, z * z));
            int b = i >> 12;              // /MM
            int c = i & (MM - 1);
            float* base = kxyz + (size_t)b * 16384 + (c >> 8) * 1024;
            const int pos = c & 255;
            base[pos] = x; base[256 + pos] = y; base[512 + pos] = z; base[768 + pos] = n;
        }
    }
}

// -------- Kernel 2: fused knn + gather-interp + 2-layer MFMA MLP ---------
// grid 512, block 1024 (16 waves). Block owns 64 queries. Phase 1: single
// SoA scan (4 b128 / 4 cands, 3 pk-fma / 2 cands) + per-super conservative
// marks + sparse rescan. Phase 2 = MLP on its own 64 points as 2 tiles.
__global__ __launch_bounds__(1024, 8) void fused_knn_mlp_kernel(
    const float* __restrict__ unknown,        // (B,N,3)
    const float* __restrict__ kxyz,           // SoA candidates (4-comp)
    const float* __restrict__ unknow_feats,   // (B,C1,N)
    const unsigned short* __restrict__ KT16,  // (B,M,C2) bf16
    const short* __restrict__ W1b, const float* __restrict__ b1,
    const short* __restrict__ W2b, const float* __restrict__ b2,
    float* __restrict__ out)                  // (B,H2,N)
{
    // 64KB: phase-1 SoA candidates | phase-2 XH(25088B)+Hs(16896B)
    __shared__ __align__(16) float candS[16384];
    // 12KB: passA pdv[16][64][3] | rescan msc[64][8] (f32) + mid[64][8] (int)
    __shared__ __align__(16) float red[3072];
    __shared__ float vf[64];
    __shared__ int   cnt[64];
    __shared__ int   IsL[64 * 3];
    __shared__ float WsL[64 * 3];

    const int bx    = blockIdx.x;             // 0..511
    const int tid   = threadIdx.x;
    const int lane  = tid & 63;
    const int w     = __builtin_amdgcn_readfirstlane(tid >> 6);  // 0..15
    const int b     = bx >> 8;
    const int qbase = (bx & 255) * 64;
    const int n     = qbase + lane;

    if (tid < 64) cnt[tid] = 0;

    // ---- stage SoA candidates (64KB) into LDS, coalesced f32x4 ----
    {
        const float* kb = kxyz + (size_t)b * 16384;
        #pragma unroll
        for (int c = 0; c < 4; ++c) {
            const int i = c * 4096 + tid * 4;
            *(f32x4*)&candS[i] = *(const f32x4*)(kb + i);
        }
    }

    // ================= Phase 1: 3-NN for this block's 64 queries =========
    {
        const float ux = unknown[((size_t)b * NN + n) * 3 + 0];
        const float uy = unknown[((size_t)b * NN + n) * 3 + 1];
        const float uz = unknown[((size_t)b * NN + n) * 3 + 2];
        const f32x2 ax2 = {-2.f * ux, -2.f * ux};
        const f32x2 ay2 = {-2.f * uy, -2.f * uy};
        const f32x2 az2 = {-2.f * uz, -2.f * uz};

        const float* kw = candS + w * 1024;   // x[256] y[256] z[256] n[256]
        __syncthreads();                      // staging visible to all waves

        // Pass A: 64 supers x 4 candidates. Chains a<-{c0,c2}, b<-{c1,c3}.
        // Per-super conservative mark: min4(s) <= fmax(va2,vb2) pre-update.
        float va0 = 3e38f, va1 = 3e38f, va2 = 3e38f;
        float vb0 = 3e38f, vb1 = 3e38f, vb2 = 3e38f;
        unsigned mlo = 0, mhi = 0;

        auto superstep = [&](int t, unsigned& mask, int bit) {
            const f32x4 X = *(const f32x4*)(kw + 4 * t);
            const f32x4 Y = *(const f32x4*)(kw + 256 + 4 * t);
            const f32x4 Z = *(const f32x4*)(kw + 512 + 4 * t);
            const f32x4 N = *(const f32x4*)(kw + 768 + 4 * t);
            const f32x2 xl = {X.x, X.y}, xh = {X.z, X.w};
            const f32x2 yl = {Y.x, Y.y}, yh = {Y.z, Y.w};
            const f32x2 zl = {Z.x, Z.y}, zh = {Z.z, Z.w};
            const f32x2 nl = {N.x, N.y}, nh = {N.z, N.w};
            const f32x2 sl = score2k(ax2, ay2, az2, xl, yl, zl, nl);  // c0,c1
            const f32x2 sh = score2k(ax2, ay2, az2, xh, yh, zh, nh);  // c2,c3
            const float thr = fmaxf(va2, vb2);                 // pre-update
            const float pm  = fminf(fminf(fminf(sl.x, sl.y), sh.x), sh.y);
            mask |= (pm <= thr) ? (1u << bit) : 0u;
            va2 = __builtin_amdgcn_fmed3f(va1, sl.x, va2);
            va1 = __builtin_amdgcn_fmed3f(va0, sl.x, va1);
            va0 = fminf(sl.x, va0);
            vb2 = __builtin_amdgcn_fmed3f(vb1, sl.y, vb2);
            vb1 = __builtin_amdgcn_fmed3f(vb0, sl.y, vb1);
            vb0 = fminf(sl.y, vb0);
            va2 = __builtin_amdgcn_fmed3f(va1, sh.x, va2);
            va1 = __builtin_amdgcn_fmed3f(va0, sh.x, va1);
            va0 = fminf(sh.x, va0);
            vb2 = __builtin_amdgcn_fmed3f(vb1, sh.y, vb2);
            vb1 = __builtin_amdgcn_fmed3f(vb0, sh.y, vb1);
            vb0 = fminf(sh.y, vb0);
        };
        #pragma unroll 2
        for (int t = 0; t < 32; ++t) superstep(t, mlo, t);
        #pragma unroll 2
        for (int t = 32; t < 64; ++t) superstep(t, mhi, t - 32);

        {   // fold chain b into chain a
            float bv[3] = {vb0, vb1, vb2};
            #pragma unroll
            for (int k = 0; k < 3; ++k) {
                float d = bv[k];
                va2 = __builtin_amdgcn_fmed3f(va1, d, va2);
                va1 = __builtin_amdgcn_fmed3f(va0, d, va1);
                va0 = fminf(d, va0);
            }
        }
        red[(w * 64 + lane) * 3 + 0] = va0;
        red[(w * 64 + lane) * 3 + 1] = va1;
        red[(w * 64 + lane) * 3 + 2] = va2;
        __syncthreads();

        if (tid < 64) {
            float r0 = 3e38f, r1 = 3e38f, r2 = 3e38f;
            #pragma unroll
            for (int ww = 0; ww < 16; ++ww) {
                #pragma unroll
                for (int k = 0; k < 3; ++k) {
                    float d = red[(ww * 64 + tid) * 3 + k];
                    r2 = __builtin_amdgcn_fmed3f(r1, d, r2);
                    r1 = __builtin_amdgcn_fmed3f(r0, d, r1);
                    r0 = fminf(d, r0);
                }
            }
            vf[tid] = r2;
        }
        __syncthreads();

        // Sparse rescan of marked supers (bit-identical score chain).
        float* mscp = red;                    // [64][8] f32 (aliases dead pdv)
        int*   midp = (int*)red + 512;        // [64][8] int
        const float v2f = vf[lane];
        auto rescan = [&](int tt) {
            const f32x4 X = *(const f32x4*)(kw + 4 * tt);
            const f32x4 Y = *(const f32x4*)(kw + 256 + 4 * tt);
            const f32x4 Z = *(const f32x4*)(kw + 512 + 4 * tt);
            const f32x4 N = *(const f32x4*)(kw + 768 + 4 * tt);
            const f32x2 xl = {X.x, X.y}, xh = {X.z, X.w};
            const f32x2 yl = {Y.x, Y.y}, yh = {Y.z, Y.w};
            const f32x2 zl = {Z.x, Z.y}, zh = {Z.z, Z.w};
            const f32x2 nl = {N.x, N.y}, nh = {N.z, N.w};
            const f32x2 sl = score2k(ax2, ay2, az2, xl, yl, zl, nl);
            const f32x2 sh = score2k(ax2, ay2, az2, xh, yh, zh, nh);
            const float sv[4] = {sl.x, sl.y, sh.x, sh.y};
            #pragma unroll
            for (int j = 0; j < 4; ++j) {
                if (sv[j] <= v2f) {
                    int slot = atomicAdd(&cnt[lane], 1);
                    if (slot < 8) {
                        mscp[lane * 8 + slot] = sv[j];
                        midp[lane * 8 + slot] = w * 256 + 4 * tt + j;
                    }
                }
            }
        };
        unsigned m = mlo;
        while (m) { int t = __builtin_ctz(m); m &= m - 1; rescan(t); }
        m = mhi;
        while (m) { int t = __builtin_ctz(m); m &= m - 1; rescan(t + 32); }
        __syncthreads();

        if (tid < 64) {
            const int c = cnt[tid] < 8 ? cnt[tid] : 8;
            float r0 = 3e38f, r1 = 3e38f, r2 = 3e38f;
            int   q0 = 0x7FFFFFFF, q1 = 0x7FFFFFFF, q2 = 0x7FFFFFFF;
            #pragma unroll
            for (int k = 0; k < 8; ++k) {
                float d = (k < c) ? mscp[tid * 8 + k] : 3e38f;
                int   j = (k < c) ? midp[tid * 8 + k] : 0x7FFFFFFF;
                const bool lt0 = (d < r0) || (d == r0 && j < q0);
                const bool lt1 = (d < r1) || (d == r1 && j < q1);
                const bool lt2 = (d < r2) || (d == r2 && j < q2);
                float nr2 = lt1 ? r1 : (lt2 ? d : r2);
                int   nq2 = lt1 ? q1 : (lt2 ? j : q2);
                float nr1 = lt0 ? r0 : (lt1 ? d : r1);
                int   nq1 = lt0 ? q0 : (lt1 ? j : q1);
                float nr0 = lt0 ? d : r0;
                int   nq0 = lt0 ? j : q0;
                r0 = nr0; r1 = nr1; r2 = nr2; q0 = nq0; q1 = nq1; q2 = nq2;
            }
            const float* up = unknown + ((size_t)b * NN + qbase + tid) * 3;
            const float uxx = up[0], uyy = up[1], uzz = up[2];
            const float unq = fmaf(uxx, uxx, fmaf(uyy, uyy, uzz * uzz));
            float d0 = sqrtf(fmaxf(r0 + unq, 0.f));
            float d1 = sqrtf(fmaxf(r1 + unq, 0.f));
            float d2 = sqrtf(fmaxf(r2 + unq, 0.f));
            float i0 = 1.f / (d0 + 1e-8f);
            float i1 = 1.f / (d1 + 1e-8f);
            float i2 = 1.f / (d2 + 1e-8f);
            float s  = i0 + i1 + i2;
            IsL[tid * 3 + 0] = q0; IsL[tid * 3 + 1] = q1; IsL[tid * 3 + 2] = q2;
            WsL[tid * 3 + 0] = i0 / s; WsL[tid * 3 + 1] = i1 / s; WsL[tid * 3 + 2] = i2 / s;
        }
    }
    __syncthreads();

    // ================= Phase 2: MLP on this block's 64 points ============
    // candidates dead -> carve XH/Hs out of the candS region.
    const unsigned short* KTb = KT16 + (size_t)b * MM * C2;
    short* XH_s = (short*)candS;              // [32][XROW]
    short* Hs_s = (short*)candS + 32 * XROW;  // [32][HROW]
    const int lr = lane & 15;
    const int lq = lane >> 4;
    const int c4 = lane << 2;                 // 0..252

    for (int tile = 0; tile < 2; ++tile) {
        const int pbase = tile * 32;

        // ---- X build: wave w -> local points 2w, 2w+1 (issue all 6 gathers)
        {
            ushort4 g[2][3];
            #pragma unroll
            for (int j = 0; j < 2; ++j) {
                const int pi = (pbase + 2 * w + j) * 3;
                g[j][0] = *(const ushort4*)(KTb + (size_t)IsL[pi + 0] * C2 + c4);
                g[j][1] = *(const ushort4*)(KTb + (size_t)IsL[pi + 1] * C2 + c4);
                g[j][2] = *(const ushort4*)(KTb + (size_t)IsL[pi + 2] * C2 + c4);
            }
            #pragma unroll
            for (int j = 0; j < 2; ++j) {
                const int pl = 2 * w + j;
                const int pi = (pbase + pl) * 3;
                const float w0 = WsL[pi + 0], w1 = WsL[pi + 1], w2 = WsL[pi + 2];
                float vx = fmaf(w0, bf16_to_f32(g[j][0].x), fmaf(w1, bf16_to_f32(g[j][1].x), w2 * bf16_to_f32(g[j][2].x)));
                float vy = fmaf(w0, bf16_to_f32(g[j][0].y), fmaf(w1, bf16_to_f32(g[j][1].y), w2 * bf16_to_f32(g[j][2].y)));
                float vz = fmaf(w0, bf16_to_f32(g[j][0].z), fmaf(w1, bf16_to_f32(g[j][1].z), w2 * bf16_to_f32(g[j][2].z)));
                float vw = fmaf(w0, bf16_to_f32(g[j][0].w), fmaf(w1, bf16_to_f32(g[j][1].w), w2 * bf16_to_f32(g[j][2].w)));
                uint2 pk;
                pk.x = pack_bf16x2(vx, vy);
                pk.y = pack_bf16x2(vz, vw);
                *(uint2*)&XH_s[pl * XROW + c4] = pk;
            }
            const float* UFb = unknow_feats + (size_t)b * C1 * NN + qbase + pbase;
            const int cc = tid >> 3;              // 0..127
            const int nq = (tid & 7) << 2;        // 0,4,..,28
            const float4 f = *(const float4*)(UFb + (size_t)cc * NN + nq);
            XH_s[(nq + 0) * XROW + C2 + cc] = f32_to_bf16(f.x);
            XH_s[(nq + 1) * XROW + C2 + cc] = f32_to_bf16(f.y);
            XH_s[(nq + 2) * XROW + C2 + cc] = f32_to_bf16(f.z);
            XH_s[(nq + 3) * XROW + C2 + cc] = f32_to_bf16(f.w);
        }
        __syncthreads();

        // ---- GEMM1: wave w -> H1 rows [16w, 16w+16), 32 points ----
        f32x4 acc1[2];
        acc1[0] = (f32x4){0.f, 0.f, 0.f, 0.f};
        acc1[1] = (f32x4){0.f, 0.f, 0.f, 0.f};
        #pragma unroll 4
        for (int k0 = 0; k0 < CIN; k0 += 32) {
            bf16x8 a  = *(const bf16x8*)(W1b + (size_t)(w * 16 + lr) * CIN + k0 + lq * 8);
            bf16x8 x0 = *(bf16x8*)&XH_s[lr * XROW + k0 + lq * 8];
            bf16x8 x1 = *(bf16x8*)&XH_s[(16 + lr) * XROW + k0 + lq * 8];
            acc1[0] = __builtin_amdgcn_mfma_f32_16x16x32_bf16(a, x0, acc1[0], 0, 0, 0);
            acc1[1] = __builtin_amdgcn_mfma_f32_16x16x32_bf16(a, x1, acc1[1], 0, 0, 0);
        }
        {
            const int ob = w * 16 + lq * 4;
            float bb0 = b1[ob + 0], bb1 = b1[ob + 1], bb2 = b1[ob + 2], bb3 = b1[ob + 3];
            #pragma unroll
            for (int p = 0; p < 2; ++p) {
                uint2 pk;
                pk.x = pack_bf16x2(fmaxf(acc1[p].x + bb0, 0.f),
                                   fmaxf(acc1[p].y + bb1, 0.f));
                pk.y = pack_bf16x2(fmaxf(acc1[p].z + bb2, 0.f),
                                   fmaxf(acc1[p].w + bb3, 0.f));
                *(uint2*)&Hs_s[(p * 16 + lr) * HROW + ob] = pk;
            }
        }
        __syncthreads();

        // ---- GEMM2: wave w -> H2 rows [16(w&7),+16), points [16(w>>3),+16)
        {
            const int r0 = (w & 7) * 16;
            const int pg = (w >> 3) * 16;
            f32x4 acc2 = (f32x4){0.f, 0.f, 0.f, 0.f};
            #pragma unroll 4
            for (int k0 = 0; k0 < H1; k0 += 32) {
                bf16x8 a2 = *(const bf16x8*)(W2b + (size_t)(r0 + lr) * H1 + k0 + lq * 8);
                bf16x8 h  = *(bf16x8*)&Hs_s[(pg + lr) * HROW + k0 + lq * 8];
                acc2 = __builtin_amdgcn_mfma_f32_16x16x32_bf16(a2, h, acc2, 0, 0, 0);
            }
            const int nn = qbase + pbase + pg + lr;
            #pragma unroll
            for (int r = 0; r < 4; ++r) {
                const int o = r0 + lq * 4 + r;
                out[((size_t)b * H2 + o) * NN + nn] =
                    fmaxf(((const float*)&acc2)[r] + b2[o], 0.f);
            }
        }
        __syncthreads();   // Hs/XH free for next tile
    }
}

extern "C" void kernel_launch(void* const* d_in, const int* in_sizes, int n_in,
                              void* d_out, int out_size, void* d_ws, size_t ws_size,
                              hipStream_t stream) {
    const float* unknown      = (const float*)d_in[0];
    const float* known        = (const float*)d_in[1];
    const float* unknow_feats = (const float*)d_in[2];
    const float* known_feats  = (const float*)d_in[3];
    const float* W1           = (const float*)d_in[4];
    const float* b1           = (const float*)d_in[5];
    const float* W2           = (const float*)d_in[6];
    const float* b2           = (const float*)d_in[7];
    float* out = (float*)d_out;

    char* ws = (char*)d_ws;
    short*          W1b  = (short*)(ws);                    // 196608 B
    short*          W2b  = (short*)(ws + 196608);           // 65536 B
    float*          kxyz = (float*)(ws + 262144);           // 131072 B
    unsigned short* KT16 = (unsigned short*)(ws + 393216);  // 4194304 B

    prep_kernel<<<2464, 256, 0, stream>>>(
        known_feats, KT16, W1, W2, W1b, W2b, known, kxyz);

    fused_knn_mlp_kernel<<<512, 1024, 0, stream>>>(
        unknown, kxyz, unknow_feats, KT16, W1b, b1, W2b, b2, out);
}

// Round 9
// 157.140 us; speedup vs baseline: 1.1489x; 1.0033x over previous
//
#include <hip/hip_runtime.h>
#include <hip/hip_bf16.h>

// PointNet2 FP: fused 3-NN + interp + concat + MLP(384->256->128), bf16 MFMA
// R9 = R8 + memory-pattern fixes (R8 showed VALU cut didn't move the wall;
// hbm_bytes/dur == measured BW -> pattern-limited paths are the suspects):
//  (1) prep transpose 64x64 tiles, bf16 in LDS (stride 65, conflict-free),
//      KT16 writes as ushort4 128B-per-row segments (was 64B).
//  (2) fused out-store via LDS: GEMM2 -> outS[128][36] f32 tile -> 1024-thr
//      cooperative float4 store, 128B contiguous per o-row (was 4 scalar
//      f32 stores/lane at 64B segments).
#define BB 2
#define NN 16384
#define MM 4096
#define C1 128
#define C2 256
#define CIN 384
#define H1 256
#define H2 128
#define XROW 392       // 384 + 8 pad
#define HROW 264       // 256 + 8 pad
#define OS   36        // outS row stride (floats): 16B-aligned, <=2-way banks

typedef __attribute__((ext_vector_type(8))) short bf16x8;
typedef __attribute__((ext_vector_type(4))) float f32x4;
typedef __attribute__((ext_vector_type(2))) float f32x2;

__device__ __forceinline__ short f32_to_bf16(float x) {
    unsigned u = __float_as_uint(x);
    u += 0x7fffu + ((u >> 16) & 1u);   // RNE
    return (short)(u >> 16);
}
__device__ __forceinline__ float bf16_to_f32(unsigned short u) {
    union { unsigned u; float f; } c; c.u = ((unsigned)u) << 16; return c.f;
}
__device__ __forceinline__ unsigned pack_bf16x2(float a, float b) {
    __hip_bfloat162 h = __float22bfloat162_rn(make_float2(a, b));
    union { __hip_bfloat162 h; unsigned u; } cv;
    cv.h = h;
    return cv.u;
}
// score PAIR with precomputed kn. MUST be bit-identical between pass A and
// the rescan (same explicit fma DAG).
__device__ __forceinline__ f32x2 score2k(f32x2 ax2, f32x2 ay2, f32x2 az2,
                                         f32x2 kx, f32x2 ky, f32x2 kz, f32x2 kn) {
    f32x2 t = __builtin_elementwise_fma(ay2, ky, kn);
    t = __builtin_elementwise_fma(ax2, kx, t);
    t = __builtin_elementwise_fma(az2, kz, t);
    return t;
}

// ---------------- Kernel 1: prep — transpose + weight cast + kxyz --------
// blocks 0..511: 64x64 transpose KF (B,C2,M) -> KT16 (B,M,C2) bf16
// blocks 512..895: weight casts; 896..927: kxyz pack. 256 thr.
__global__ __launch_bounds__(256) void prep_kernel(
    const float* __restrict__ KF, unsigned short* __restrict__ KT16,
    const float* __restrict__ W1, const float* __restrict__ W2,
    short* __restrict__ W1b, short* __restrict__ W2b,
    const float* __restrict__ known, float* __restrict__ kxyz)
{
    const int bx  = blockIdx.x;
    const int tid = threadIdx.x;
    if (bx < 512) {
        __shared__ short tlb[64 * 65];     // [c][m], stride 65 (odd)
        const int tb = bx >> 8;            // batch
        const int c0 = ((bx >> 6) & 3) * 64;
        const int m0 = (bx & 63) * 64;
        const int tr  = tid >> 4;          // 0..15
        const int tc4 = (tid & 15) * 4;    // 0..60
        #pragma unroll
        for (int p = 0; p < 4; ++p) {
            const int c = tr + p * 16;
            const float4 f = *(const float4*)(
                KF + ((size_t)tb * C2 + c0 + c) * MM + m0 + tc4);
            tlb[c * 65 + tc4 + 0] = f32_to_bf16(f.x);
            tlb[c * 65 + tc4 + 1] = f32_to_bf16(f.y);
            tlb[c * 65 + tc4 + 2] = f32_to_bf16(f.z);
            tlb[c * 65 + tc4 + 3] = f32_to_bf16(f.w);
        }
        __syncthreads();
        #pragma unroll
        for (int p = 0; p < 4; ++p) {
            const int m = tr + p * 16;
            ushort4 v;
            v.x = (unsigned short)tlb[(tc4 + 0) * 65 + m];
            v.y = (unsigned short)tlb[(tc4 + 1) * 65 + m];
            v.z = (unsigned short)tlb[(tc4 + 2) * 65 + m];
            v.w = (unsigned short)tlb[(tc4 + 3) * 65 + m];
            *(ushort4*)(KT16 + ((size_t)tb * MM + m0 + m) * C2 + c0 + tc4) = v;
        }
    } else if (bx < 896) {
        int i = (bx - 512) * 256 + tid;    // 0..98303
        W1b[i] = f32_to_bf16(W1[i]);       // W1 is exactly 98304 elements
        if (i < H2 * H1) W2b[i] = f32_to_bf16(W2[i]);
    } else {
        // kxyz: SoA by 256-candidate slice: [b][slice(16)][comp(4)][256]
        int i = (bx - 896) * 256 + tid;
        if (i < BB * MM) {
            float x = known[3 * i + 0], y = known[3 * i + 1], z = known[3 * i + 2];
            float n = fmaf(x, x, fmaf(y, y, z * z));
            int b = i >> 12;              // /MM
            int c = i & (MM - 1);
            float* base = kxyz + (size_t)b * 16384 + (c >> 8) * 1024;
            const int pos = c & 255;
            base[pos] = x; base[256 + pos] = y; base[512 + pos] = z; base[768 + pos] = n;
        }
    }
}

// -------- Kernel 2: fused knn + gather-interp + 2-layer MFMA MLP ---------
// grid 512, block 1024 (16 waves). Block owns 64 queries. Phase 1: single
// SoA scan + per-super conservative marks + sparse rescan. Phase 2 = MLP
// on its own 64 points as 2 tiles, out via LDS-staged coalesced store.
__global__ __launch_bounds__(1024, 8) void fused_knn_mlp_kernel(
    const float* __restrict__ unknown,        // (B,N,3)
    const float* __restrict__ kxyz,           // SoA candidates (4-comp)
    const float* __restrict__ unknow_feats,   // (B,C1,N)
    const unsigned short* __restrict__ KT16,  // (B,M,C2) bf16
    const short* __restrict__ W1b, const float* __restrict__ b1,
    const short* __restrict__ W2b, const float* __restrict__ b2,
    float* __restrict__ out)                  // (B,H2,N)
{
    // 64KB: phase-1 SoA candidates | phase-2 XH(25088B)+Hs(16896B);
    // outS[128][OS] f32 (18432B) aliases the XH region during GEMM2/store.
    __shared__ __align__(16) float candS[16384];
    // 12KB: passA pdv[16][64][3] | rescan msc[64][8] (f32) + mid[64][8] (int)
    __shared__ __align__(16) float red[3072];
    __shared__ float vf[64];
    __shared__ int   cnt[64];
    __shared__ int   IsL[64 * 3];
    __shared__ float WsL[64 * 3];

    const int bx    = blockIdx.x;             // 0..511
    const int tid   = threadIdx.x;
    const int lane  = tid & 63;
    const int w     = __builtin_amdgcn_readfirstlane(tid >> 6);  // 0..15
    const int b     = bx >> 8;
    const int qbase = (bx & 255) * 64;
    const int n     = qbase + lane;

    if (tid < 64) cnt[tid] = 0;

    // ---- stage SoA candidates (64KB) into LDS, coalesced f32x4 ----
    {
        const float* kb = kxyz + (size_t)b * 16384;
        #pragma unroll
        for (int c = 0; c < 4; ++c) {
            const int i = c * 4096 + tid * 4;
            *(f32x4*)&candS[i] = *(const f32x4*)(kb + i);
        }
    }

    // ================= Phase 1: 3-NN for this block's 64 queries =========
    {
        const float ux = unknown[((size_t)b * NN + n) * 3 + 0];
        const float uy = unknown[((size_t)b * NN + n) * 3 + 1];
        const float uz = unknown[((size_t)b * NN + n) * 3 + 2];
        const f32x2 ax2 = {-2.f * ux, -2.f * ux};
        const f32x2 ay2 = {-2.f * uy, -2.f * uy};
        const f32x2 az2 = {-2.f * uz, -2.f * uz};

        const float* kw = candS + w * 1024;   // x[256] y[256] z[256] n[256]
        __syncthreads();                      // staging visible to all waves

        // Pass A: 64 supers x 4 candidates. Chains a<-{c0,c2}, b<-{c1,c3}.
        // Per-super conservative mark: min4(s) <= fmax(va2,vb2) pre-update.
        float va0 = 3e38f, va1 = 3e38f, va2 = 3e38f;
        float vb0 = 3e38f, vb1 = 3e38f, vb2 = 3e38f;
        unsigned mlo = 0, mhi = 0;

        auto superstep = [&](int t, unsigned& mask, int bit) {
            const f32x4 X = *(const f32x4*)(kw + 4 * t);
            const f32x4 Y = *(const f32x4*)(kw + 256 + 4 * t);
            const f32x4 Z = *(const f32x4*)(kw + 512 + 4 * t);
            const f32x4 N = *(const f32x4*)(kw + 768 + 4 * t);
            const f32x2 xl = {X.x, X.y}, xh = {X.z, X.w};
            const f32x2 yl = {Y.x, Y.y}, yh = {Y.z, Y.w};
            const f32x2 zl = {Z.x, Z.y}, zh = {Z.z, Z.w};
            const f32x2 nl = {N.x, N.y}, nh = {N.z, N.w};
            const f32x2 sl = score2k(ax2, ay2, az2, xl, yl, zl, nl);  // c0,c1
            const f32x2 sh = score2k(ax2, ay2, az2, xh, yh, zh, nh);  // c2,c3
            const float thr = fmaxf(va2, vb2);                 // pre-update
            const float pm  = fminf(fminf(fminf(sl.x, sl.y), sh.x), sh.y);
            mask |= (pm <= thr) ? (1u << bit) : 0u;
            va2 = __builtin_amdgcn_fmed3f(va1, sl.x, va2);
            va1 = __builtin_amdgcn_fmed3f(va0, sl.x, va1);
            va0 = fminf(sl.x, va0);
            vb2 = __builtin_amdgcn_fmed3f(vb1, sl.y, vb2);
            vb1 = __builtin_amdgcn_fmed3f(vb0, sl.y, vb1);
            vb0 = fminf(sl.y, vb0);
            va2 = __builtin_amdgcn_fmed3f(va1, sh.x, va2);
            va1 = __builtin_amdgcn_fmed3f(va0, sh.x, va1);
            va0 = fminf(sh.x, va0);
            vb2 = __builtin_amdgcn_fmed3f(vb1, sh.y, vb2);
            vb1 = __builtin_amdgcn_fmed3f(vb0, sh.y, vb1);
            vb0 = fminf(sh.y, vb0);
        };
        #pragma unroll 2
        for (int t = 0; t < 32; ++t) superstep(t, mlo, t);
        #pragma unroll 2
        for (int t = 32; t < 64; ++t) superstep(t, mhi, t - 32);

        {   // fold chain b into chain a
            float bv[3] = {vb0, vb1, vb2};
            #pragma unroll
            for (int k = 0; k < 3; ++k) {
                float d = bv[k];
                va2 = __builtin_amdgcn_fmed3f(va1, d, va2);
                va1 = __builtin_amdgcn_fmed3f(va0, d, va1);
                va0 = fminf(d, va0);
            }
        }
        red[(w * 64 + lane) * 3 + 0] = va0;
        red[(w * 64 + lane) * 3 + 1] = va1;
        red[(w * 64 + lane) * 3 + 2] = va2;
        __syncthreads();

        if (tid < 64) {
            float r0 = 3e38f, r1 = 3e38f, r2 = 3e38f;
            #pragma unroll
            for (int ww = 0; ww < 16; ++ww) {
                #pragma unroll
                for (int k = 0; k < 3; ++k) {
                    float d = red[(ww * 64 + tid) * 3 + k];
                    r2 = __builtin_amdgcn_fmed3f(r1, d, r2);
                    r1 = __builtin_amdgcn_fmed3f(r0, d, r1);
                    r0 = fminf(d, r0);
                }
            }
            vf[tid] = r2;
        }
        __syncthreads();

        // Sparse rescan of marked supers (bit-identical score chain).
        float* mscp = red;                    // [64][8] f32 (aliases dead pdv)
        int*   midp = (int*)red + 512;        // [64][8] int
        const float v2f = vf[lane];
        auto rescan = [&](int tt) {
            const f32x4 X = *(const f32x4*)(kw + 4 * tt);
            const f32x4 Y = *(const f32x4*)(kw + 256 + 4 * tt);
            const f32x4 Z = *(const f32x4*)(kw + 512 + 4 * tt);
            const f32x4 N = *(const f32x4*)(kw + 768 + 4 * tt);
            const f32x2 xl = {X.x, X.y}, xh = {X.z, X.w};
            const f32x2 yl = {Y.x, Y.y}, yh = {Y.z, Y.w};
            const f32x2 zl = {Z.x, Z.y}, zh = {Z.z, Z.w};
            const f32x2 nl = {N.x, N.y}, nh = {N.z, N.w};
            const f32x2 sl = score2k(ax2, ay2, az2, xl, yl, zl, nl);
            const f32x2 sh = score2k(ax2, ay2, az2, xh, yh, zh, nh);
            const float sv[4] = {sl.x, sl.y, sh.x, sh.y};
            #pragma unroll
            for (int j = 0; j < 4; ++j) {
                if (sv[j] <= v2f) {
                    int slot = atomicAdd(&cnt[lane], 1);
                    if (slot < 8) {
                        mscp[lane * 8 + slot] = sv[j];
                        midp[lane * 8 + slot] = w * 256 + 4 * tt + j;
                    }
                }
            }
        };
        unsigned m = mlo;
        while (m) { int t = __builtin_ctz(m); m &= m - 1; rescan(t); }
        m = mhi;
        while (m) { int t = __builtin_ctz(m); m &= m - 1; rescan(t + 32); }
        __syncthreads();

        if (tid < 64) {
            const int c = cnt[tid] < 8 ? cnt[tid] : 8;
            float r0 = 3e38f, r1 = 3e38f, r2 = 3e38f;
            int   q0 = 0x7FFFFFFF, q1 = 0x7FFFFFFF, q2 = 0x7FFFFFFF;
            #pragma unroll
            for (int k = 0; k < 8; ++k) {
                float d = (k < c) ? mscp[tid * 8 + k] : 3e38f;
                int   j = (k < c) ? midp[tid * 8 + k] : 0x7FFFFFFF;
                const bool lt0 = (d < r0) || (d == r0 && j < q0);
                const bool lt1 = (d < r1) || (d == r1 && j < q1);
                const bool lt2 = (d < r2) || (d == r2 && j < q2);
                float nr2 = lt1 ? r1 : (lt2 ? d : r2);
                int   nq2 = lt1 ? q1 : (lt2 ? j : q2);
                float nr1 = lt0 ? r0 : (lt1 ? d : r1);
                int   nq1 = lt0 ? q0 : (lt1 ? j : q1);
                float nr0 = lt0 ? d : r0;
                int   nq0 = lt0 ? j : q0;
                r0 = nr0; r1 = nr1; r2 = nr2; q0 = nq0; q1 = nq1; q2 = nq2;
            }
            const float* up = unknown + ((size_t)b * NN + qbase + tid) * 3;
            const float uxx = up[0], uyy = up[1], uzz = up[2];
            const float unq = fmaf(uxx, uxx, fmaf(uyy, uyy, uzz * uzz));
            float d0 = sqrtf(fmaxf(r0 + unq, 0.f));
            float d1 = sqrtf(fmaxf(r1 + unq, 0.f));
            float d2 = sqrtf(fmaxf(r2 + unq, 0.f));
            float i0 = 1.f / (d0 + 1e-8f);
            float i1 = 1.f / (d1 + 1e-8f);
            float i2 = 1.f / (d2 + 1e-8f);
            float s  = i0 + i1 + i2;
            IsL[tid * 3 + 0] = q0; IsL[tid * 3 + 1] = q1; IsL[tid * 3 + 2] = q2;
            WsL[tid * 3 + 0] = i0 / s; WsL[tid * 3 + 1] = i1 / s; WsL[tid * 3 + 2] = i2 / s;
        }
    }
    __syncthreads();

    // ================= Phase 2: MLP on this block's 64 points ============
    // candidates dead -> carve XH/Hs out of the candS region.
    const unsigned short* KTb = KT16 + (size_t)b * MM * C2;
    short* XH_s = (short*)candS;              // [32][XROW]
    short* Hs_s = (short*)candS + 32 * XROW;  // [32][HROW]
    float* outS = candS;                      // [128][OS] (aliases XH region)
    const int lr = lane & 15;
    const int lq = lane >> 4;
    const int c4 = lane << 2;                 // 0..252

    for (int tile = 0; tile < 2; ++tile) {
        const int pbase = tile * 32;

        // ---- X build: wave w -> local points 2w, 2w+1 (issue all 6 gathers)
        {
            ushort4 g[2][3];
            #pragma unroll
            for (int j = 0; j < 2; ++j) {
                const int pi = (pbase + 2 * w + j) * 3;
                g[j][0] = *(const ushort4*)(KTb + (size_t)IsL[pi + 0] * C2 + c4);
                g[j][1] = *(const ushort4*)(KTb + (size_t)IsL[pi + 1] * C2 + c4);
                g[j][2] = *(const ushort4*)(KTb + (size_t)IsL[pi + 2] * C2 + c4);
            }
            #pragma unroll
            for (int j = 0; j < 2; ++j) {
                const int pl = 2 * w + j;
                const int pi = (pbase + pl) * 3;
                const float w0 = WsL[pi + 0], w1 = WsL[pi + 1], w2 = WsL[pi + 2];
                float vx = fmaf(w0, bf16_to_f32(g[j][0].x), fmaf(w1, bf16_to_f32(g[j][1].x), w2 * bf16_to_f32(g[j][2].x)));
                float vy = fmaf(w0, bf16_to_f32(g[j][0].y), fmaf(w1, bf16_to_f32(g[j][1].y), w2 * bf16_to_f32(g[j][2].y)));
                float vz = fmaf(w0, bf16_to_f32(g[j][0].z), fmaf(w1, bf16_to_f32(g[j][1].z), w2 * bf16_to_f32(g[j][2].z)));
                float vw = fmaf(w0, bf16_to_f32(g[j][0].w), fmaf(w1, bf16_to_f32(g[j][1].w), w2 * bf16_to_f32(g[j][2].w)));
                uint2 pk;
                pk.x = pack_bf16x2(vx, vy);
                pk.y = pack_bf16x2(vz, vw);
                *(uint2*)&XH_s[pl * XROW + c4] = pk;
            }
            const float* UFb = unknow_feats + (size_t)b * C1 * NN + qbase + pbase;
            const int cc = tid >> 3;              // 0..127
            const int nq = (tid & 7) << 2;        // 0,4,..,28
            const float4 f = *(const float4*)(UFb + (size_t)cc * NN + nq);
            XH_s[(nq + 0) * XROW + C2 + cc] = f32_to_bf16(f.x);
            XH_s[(nq + 1) * XROW + C2 + cc] = f32_to_bf16(f.y);
            XH_s[(nq + 2) * XROW + C2 + cc] = f32_to_bf16(f.z);
            XH_s[(nq + 3) * XROW + C2 + cc] = f32_to_bf16(f.w);
        }
        __syncthreads();

        // ---- GEMM1: wave w -> H1 rows [16w, 16w+16), 32 points ----
        f32x4 acc1[2];
        acc1[0] = (f32x4){0.f, 0.f, 0.f, 0.f};
        acc1[1] = (f32x4){0.f, 0.f, 0.f, 0.f};
        #pragma unroll 4
        for (int k0 = 0; k0 < CIN; k0 += 32) {
            bf16x8 a  = *(const bf16x8*)(W1b + (size_t)(w * 16 + lr) * CIN + k0 + lq * 8);
            bf16x8 x0 = *(bf16x8*)&XH_s[lr * XROW + k0 + lq * 8];
            bf16x8 x1 = *(bf16x8*)&XH_s[(16 + lr) * XROW + k0 + lq * 8];
            acc1[0] = __builtin_amdgcn_mfma_f32_16x16x32_bf16(a, x0, acc1[0], 0, 0, 0);
            acc1[1] = __builtin_amdgcn_mfma_f32_16x16x32_bf16(a, x1, acc1[1], 0, 0, 0);
        }
        {
            const int ob = w * 16 + lq * 4;
            float bb0 = b1[ob + 0], bb1 = b1[ob + 1], bb2 = b1[ob + 2], bb3 = b1[ob + 3];
            #pragma unroll
            for (int p = 0; p < 2; ++p) {
                uint2 pk;
                pk.x = pack_bf16x2(fmaxf(acc1[p].x + bb0, 0.f),
                                   fmaxf(acc1[p].y + bb1, 0.f));
                pk.y = pack_bf16x2(fmaxf(acc1[p].z + bb2, 0.f),
                                   fmaxf(acc1[p].w + bb3, 0.f));
                *(uint2*)&Hs_s[(p * 16 + lr) * HROW + ob] = pk;
            }
        }
        __syncthreads();   // Hs ready; XH dead -> outS may use its region

        // ---- GEMM2: wave w -> H2 rows [16(w&7),+16), points [16(w>>3),+16)
        {
            const int r0 = (w & 7) * 16;
            const int pg = (w >> 3) * 16;
            f32x4 acc2 = (f32x4){0.f, 0.f, 0.f, 0.f};
            #pragma unroll 4
            for (int k0 = 0; k0 < H1; k0 += 32) {
                bf16x8 a2 = *(const bf16x8*)(W2b + (size_t)(r0 + lr) * H1 + k0 + lq * 8);
                bf16x8 h  = *(bf16x8*)&Hs_s[(pg + lr) * HROW + k0 + lq * 8];
                acc2 = __builtin_amdgcn_mfma_f32_16x16x32_bf16(a2, h, acc2, 0, 0, 0);
            }
            // stage to outS[o][nn_local] (+bias+relu), nn_local in [0,32)
            #pragma unroll
            for (int r = 0; r < 4; ++r) {
                const int o = r0 + lq * 4 + r;
                outS[o * OS + pg + lr] =
                    fmaxf(((const float*)&acc2)[r] + b2[o], 0.f);
            }
        }
        __syncthreads();

        // ---- cooperative coalesced out store: 128 rows x 128B float4 ----
        {
            const int o = tid >> 3;               // 0..127
            const int k = (tid & 7) << 2;         // 0,4,..,28
            const f32x4 v = *(const f32x4*)&outS[o * OS + k];
            *(f32x4*)(out + ((size_t)b * H2 + o) * NN + qbase + pbase + k) = v;
        }
        __syncthreads();   // outS/XH/Hs free for next tile
    }
}

extern "C" void kernel_launch(void* const* d_in, const int* in_sizes, int n_in,
                              void* d_out, int out_size, void* d_ws, size_t ws_size,
                              hipStream_t stream) {
    const float* unknown      = (const float*)d_in[0];
    const float* known        = (const float*)d_in[1];
    const float* unknow_feats = (const float*)d_in[2];
    const float* known_feats  = (const float*)d_in[3];
    const float* W1           = (const float*)d_in[4];
    const float* b1           = (const float*)d_in[5];
    const float* W2           = (const float*)d_in[6];
    const float* b2           = (const float*)d_in[7];
    float* out = (float*)d_out;

    char* ws = (char*)d_ws;
    short*          W1b  = (short*)(ws);                    // 196608 B
    short*          W2b  = (short*)(ws + 196608);           // 65536 B
    float*          kxyz = (float*)(ws + 262144);           // 131072 B
    unsigned short* KT16 = (unsigned short*)(ws + 393216);  // 4194304 B

    prep_kernel<<<928, 256, 0, stream>>>(
        known_feats, KT16, W1, W2, W1b, W2b, known, kxyz);

    fused_knn_mlp_kernel<<<512, 1024, 0, stream>>>(
        unknown, kxyz, unknow_feats, KT16, W1b, b1, W2b, b2, out);
}